// Round 17
// baseline (1016.374 us; speedup 1.0000x reference)
//
#include <hip/hip_runtime.h>
#include <hip/hip_bf16.h>
#include <math.h>

#define NN 20000
#define NE 256000
#define NODE_DIM_ 128
#define EDGE_DIM_ 8
#define HID 64
#define HEADS 4
#define NLAYERS 3
#define NCLASSES 3
#define NGRAPHS 64
#define HC 256  // HEADS*HID
#define NPB 8   // nodes per block in qkv
#define ECHUNK 256
#define EB 64   // edges per block in edge_mlp

typedef __hip_bfloat16 bf16;

__device__ __forceinline__ float B2F(bf16 x) { return __bfloat162float(x); }
__device__ __forceinline__ bf16 F2B(float x) { return __float2bfloat16(x); }
__device__ __forceinline__ int clampi(int x, int lo, int hi) { return min(max(x, lo), hi); }

// ---------------- diagnostics ----------------
__global__ void gt_write_const(float* out, int n, float val) {
    int i = blockIdx.x * blockDim.x + threadIdx.x;
    if (i < n) out[i] = val;
}

// ---------------- utility ----------------
__global__ void gt_zero_i32(int* p, int n) {
    int i = blockIdx.x * blockDim.x + threadIdx.x;
    if (i < n) p[i] = 0;
}

// WeT[l][c*HC + h*64 + j] = We[l][j*HC + h*64 + c]  (fp32)
__global__ void gt_transpose_we(const float* __restrict__ We, float* __restrict__ WeT) {
    int idx = blockIdx.x * blockDim.x + threadIdx.x;
    if (idx >= NLAYERS * HID * HC) return;
    int l = idx / (HID * HC);
    int r = idx % (HID * HC);
    int c = r / HC;
    int u = r % HC;
    int hh = u >> 6, j = u & 63;
    WeT[idx] = We[(size_t)l * HID * HC + (size_t)j * HC + hh * 64 + c];
}

// ---------------- h = x @ node_W + node_b  (4 nodes/block) ----------------
__global__ void gt_node_proj(const float* __restrict__ x, const float* __restrict__ W,
                             const float* __restrict__ b, float* __restrict__ h) {
    int t = threadIdx.x;
    int n = blockIdx.x * 4 + (t >> 6);
    int c = t & 63;
    __shared__ float xr[4][NODE_DIM_];
    for (int i = t; i < 4 * NODE_DIM_; i += 256) {
        int nn = blockIdx.x * 4 + i / NODE_DIM_;
        xr[i / NODE_DIM_][i % NODE_DIM_] = (nn < NN) ? x[(size_t)nn * NODE_DIM_ + i % NODE_DIM_] : 0.f;
    }
    __syncthreads();
    if (n >= NN) return;
    float acc = 0.f;
#pragma unroll 8
    for (int j = 0; j < NODE_DIM_; ++j) acc += xr[t >> 6][j] * W[j * HID + c];
    h[(size_t)n * HID + c] = acc + b[c];
}

// ---------------- edge MLP: 64-edge GEMM tile per block, bf16 out ----------------
__global__ void gt_edge_mlp(const float* __restrict__ ea, const float* __restrict__ W1,
                            const float* __restrict__ b1, const float* __restrict__ W2,
                            const float* __restrict__ b2, bf16* __restrict__ ef) {
    int t = threadIdx.x;
    int c = t & 63, slot = t >> 6;
    int e0 = blockIdx.x * EB;
    __shared__ float aS[EB][EDGE_DIM_];
    __shared__ float t1s[EB][HID];
    for (int i = t; i < EB * EDGE_DIM_; i += 256) {
        ((float*)aS)[i] = ea[(size_t)e0 * EDGE_DIM_ + i];
    }
    float w1r[EDGE_DIM_];
#pragma unroll
    for (int j = 0; j < EDGE_DIM_; ++j) w1r[j] = W1[j * HID + c];
    float b1c = b1[c], b2c = b2[c];
    __syncthreads();
#pragma unroll
    for (int es16 = 0; es16 < 16; ++es16) {
        int es = slot * 16 + es16;
        float acc = b1c;
#pragma unroll
        for (int j = 0; j < EDGE_DIM_; ++j) acc += aS[es][j] * w1r[j];
        t1s[es][c] = fmaxf(acc, 0.f);
    }
    __syncthreads();
    float acc2[16];
#pragma unroll
    for (int i = 0; i < 16; ++i) acc2[i] = b2c;
    for (int j = 0; j < HID; ++j) {
        float w = W2[j * HID + c];
#pragma unroll
        for (int es16 = 0; es16 < 16; ++es16) acc2[es16] += t1s[slot * 16 + es16][j] * w;
    }
#pragma unroll
    for (int es16 = 0; es16 < 16; ++es16) {
        int es = slot * 16 + es16;
        ef[(size_t)(e0 + es) * HID + c] = F2B(acc2[es16]);
    }
}

// ---------------- CSR build over dst ----------------
__global__ void gt_count_dst(const int* __restrict__ ei, int* cnt) {
    int e = blockIdx.x * blockDim.x + threadIdx.x;
    if (e < NE) {
        int d = clampi(ei[NE + e], 0, NN - 1);
        atomicAdd(&cnt[d], 1);
    }
}

__global__ void gt_scan_csr(const int* __restrict__ cnt, int* __restrict__ rp, int* __restrict__ cur) {
    __shared__ int part[256];
    int tid = threadIdx.x;
    const int CH = (NN + 255) / 256;
    int s0 = tid * CH, s1 = min(s0 + CH, NN);
    int s = 0;
    for (int i = s0; i < s1; ++i) s += cnt[i];
    part[tid] = s;
    __syncthreads();
    for (int off = 1; off < 256; off <<= 1) {
        int vv = (tid >= off) ? part[tid - off] : 0;
        __syncthreads();
        if (tid >= off) part[tid] += vv;
        __syncthreads();
    }
    int base = (tid == 0) ? 0 : part[tid - 1];
    for (int i = s0; i < s1; ++i) {
        rp[i] = base;
        cur[i] = base;
        base += cnt[i];
    }
    if (tid == 255) rp[NN] = part[255];
}

__global__ void gt_fill_csr(const int* __restrict__ ei, int* cur, int* csr) {
    int e = blockIdx.x * blockDim.x + threadIdx.x;
    if (e < NE) {
        int d = clampi(ei[NE + e], 0, NN - 1);
        int pos = atomicAdd(&cur[d], 1);
        if (pos >= 0 && pos < NE) csr[pos] = e;
    }
}

// ---------------- q,k,v,qe projections (8 nodes/block); fp32 weights, bf16 k/v out ----------------
__global__ void gt_qkv_qe(const float* __restrict__ h, const float* __restrict__ Wq,
                          const float* __restrict__ bq, const float* __restrict__ Wk,
                          const float* __restrict__ bk, const float* __restrict__ Wv,
                          const float* __restrict__ bv, const float* __restrict__ WeT,
                          float* __restrict__ q, bf16* __restrict__ k, bf16* __restrict__ v,
                          float* __restrict__ qe) {
    int t = threadIdx.x;
    int n0 = blockIdx.x * NPB;
    __shared__ float hs[NPB][HID];
    __shared__ float qs[NPB][HC];
    for (int i = t; i < NPB * HID; i += 256) {
        int nn = n0 + i / HID;
        hs[i / HID][i % HID] = (nn < NN) ? h[(size_t)nn * HID + i % HID] : 0.f;
    }
    __syncthreads();
    float aq[NPB], ak[NPB], av[NPB];
#pragma unroll
    for (int i = 0; i < NPB; ++i) { aq[i] = 0.f; ak[i] = 0.f; av[i] = 0.f; }
    for (int j = 0; j < HID; ++j) {
        float wq = Wq[j * HC + t];
        float wk = Wk[j * HC + t];
        float wv = Wv[j * HC + t];
#pragma unroll
        for (int i = 0; i < NPB; ++i) {
            aq[i] += hs[i][j] * wq;
            ak[i] += hs[i][j] * wk;
            av[i] += hs[i][j] * wv;
        }
    }
    float bqv = bq[t], bkv = bk[t], bvv = bv[t];
    for (int i = 0; i < NPB; ++i) {
        int nn = n0 + i;
        float qr = aq[i] + bqv;
        qs[i][t] = qr;
        if (nn < NN) {
            q[(size_t)nn * HC + t] = qr;
            k[(size_t)nn * HC + t] = F2B(ak[i] + bkv);
            v[(size_t)nn * HC + t] = F2B(av[i] + bvv);
        }
    }
    __syncthreads();
    int h2 = t >> 6;
    float accq[NPB];
#pragma unroll
    for (int i = 0; i < NPB; ++i) accq[i] = 0.f;
    for (int c = 0; c < HID; ++c) {
        float wt = WeT[(size_t)c * HC + t];
#pragma unroll
        for (int i = 0; i < NPB; ++i) accq[i] += qs[i][h2 * 64 + c] * wt;
    }
    for (int i = 0; i < NPB; ++i) {
        int nn = n0 + i;
        if (nn < NN) qe[(size_t)nn * HC + t] = accq[i];
    }
}

// ---------------- FUSED attn: 4-edge/wave alpha + exp precompute + online softmax + agg + LN ----------------
__global__ void gt_attn_fused(const float* __restrict__ q, const float* __restrict__ qe,
                              const bf16* __restrict__ k, const bf16* __restrict__ v,
                              const bf16* __restrict__ ef, const float* __restrict__ We,
                              const int* __restrict__ rp, const int* __restrict__ csr,
                              const int* __restrict__ ei, const float* __restrict__ Wskip,
                              const float* __restrict__ bskip, const float* __restrict__ lng,
                              const float* __restrict__ lnb, float* __restrict__ h) {
    int n = blockIdx.x;
    int t = threadIdx.x;   // 256 = 4 waves; accumulate phase: wave == head
    int lane = t & 63, wave = t >> 6;
    __shared__ float sQ[HC];
    __shared__ float sQe[HC];
    __shared__ int sE[ECHUNK];
    __shared__ int sSrc[ECHUNK];
    __shared__ float4 sAl[ECHUNK];
    __shared__ float sW[HEADS][ECHUNK];
    __shared__ float sS[HC];
    __shared__ float sC[HC];
    __shared__ float res[HID];
    sQ[t] = q[(size_t)n * HC + t];
    sQe[t] = qe[(size_t)n * HC + t];
    if (t < HID) res[t] = h[(size_t)n * HID + t];
    int s0 = clampi(rp[n], 0, NE), s1 = clampi(rp[n + 1], s0, NE);
    float mrun = -1e30f, lrun = 0.f, accv = 0.f, accs = 0.f;
    int esub = lane >> 4, c16 = lane & 15;
    for (int base = s0; base < s1; base += ECHUNK) {
        int m = min(ECHUNK, s1 - base);
        __syncthreads();
        if (t < m) {
            int e = clampi(csr[base + t], 0, NE - 1);
            sE[t] = e;
            sSrc[t] = clampi(ei[e], 0, NN - 1);
        }
        __syncthreads();
        // alpha: each wave does 4 edges at once; 16-lane group per edge
        for (int i0 = wave * 4; i0 < m; i0 += 16) {
            int i = i0 + esub;
            float ph0 = 0.f, ph1 = 0.f, ph2 = 0.f, ph3 = 0.f;
            if (i < m) {
                const bf16* kk = &k[(size_t)sSrc[i] * HC];
                const bf16* ep = &ef[(size_t)sE[i] * HID];
#pragma unroll
                for (int j = 0; j < 4; ++j) {
                    int c = c16 + 16 * j;
                    float efc = B2F(ep[c]);
                    ph0 += sQ[c] * B2F(kk[c]) + sQe[c] * efc;
                    ph1 += sQ[64 + c] * B2F(kk[64 + c]) + sQe[64 + c] * efc;
                    ph2 += sQ[128 + c] * B2F(kk[128 + c]) + sQe[128 + c] * efc;
                    ph3 += sQ[192 + c] * B2F(kk[192 + c]) + sQe[192 + c] * efc;
                }
            }
#pragma unroll
            for (int s = 8; s > 0; s >>= 1) {  // 16-lane group reduction
                ph0 += __shfl_down(ph0, s, 64);
                ph1 += __shfl_down(ph1, s, 64);
                ph2 += __shfl_down(ph2, s, 64);
                ph3 += __shfl_down(ph3, s, 64);
            }
            if (c16 == 0 && i < m) {
                float4 r;
                r.x = ph0 * 0.125f; r.y = ph1 * 0.125f; r.z = ph2 * 0.125f; r.w = ph3 * 0.125f;
                sAl[i] = r;
            }
        }
        __syncthreads();
        // chunk max for this wave's head
        float cmax = -1e30f;
        for (int i = lane; i < m; i += 64) cmax = fmaxf(cmax, ((const float*)&sAl[i])[wave]);
#pragma unroll
        for (int s = 32; s > 0; s >>= 1) cmax = fmaxf(cmax, __shfl_xor(cmax, s, 64));
        float newm = fmaxf(mrun, cmax);
        float scale = __expf(mrun - newm);
        accv *= scale; accs *= scale; lrun *= scale;
        mrun = newm;
        // exp precompute: one exp per (edge, head); wave handles its own head row
        for (int i = lane; i < m; i += 64)
            sW[wave][i] = __expf(((const float*)&sAl[i])[wave] - mrun);
        // wave-coherent: each thread reads only sW[wave][*], written by its own wave
#pragma unroll 4
        for (int i = 0; i < m; ++i) {
            float wgt = sW[wave][i];
            lrun += wgt;
            accv += wgt * B2F(v[(size_t)sSrc[i] * HC + t]);
            accs += wgt * B2F(ef[(size_t)sE[i] * HID + lane]);
        }
    }
    float inv = (s1 > s0) ? (1.f / lrun) : 0.f;
    sS[t] = accs * inv;
    float accvn = accv * inv;
    __syncthreads();
    float proj = 0.f;
    const float* srow = &sS[wave * 64];
#pragma unroll 8
    for (int j = 0; j < HID; ++j) proj += srow[j] * We[(size_t)j * HC + t];
    sC[t] = accvn + proj;
    __syncthreads();
    if (t < HID) {
        float conv = 0.25f * (sC[t] + sC[HID + t] + sC[2 * HID + t] + sC[3 * HID + t]);
        float sk = bskip[t];
#pragma unroll 8
        for (int j = 0; j < HID; ++j) sk += res[j] * Wskip[j * HID + t];
        float y = conv + sk + res[t];
        float mm = y;
#pragma unroll
        for (int s = 32; s > 0; s >>= 1) mm += __shfl_xor(mm, s, 64);
        mm *= (1.f / HID);
        float d = y - mm;
        float vv = d * d;
#pragma unroll
        for (int s = 32; s > 0; s >>= 1) vv += __shfl_xor(vv, s, 64);
        vv *= (1.f / HID);
        float o = d * rsqrtf(vv + 1e-5f) * lng[t] + lnb[t];
        h[(size_t)n * HID + t] = fmaxf(o, 0.f);
    }
}

// ---------------- pool (true count) + classifier ----------------
__global__ void gt_pool_classify(const float* __restrict__ h, const int* __restrict__ batch,
                                 const float* __restrict__ W, const float* __restrict__ b,
                                 float* __restrict__ out) {
    int g = blockIdx.x;
    int c = threadIdx.x;
    __shared__ float pooled[HID];
    __shared__ float lg[4];
    __shared__ int bounds[2];
    if (c < 2) {
        int target = g + c;
        int lo = 0, hi = NN;
        while (lo < hi) {
            int mid = (lo + hi) >> 1;
            if (batch[mid] < target) lo = mid + 1; else hi = mid;
        }
        bounds[c] = lo;
    }
    __syncthreads();
    int n0 = bounds[0], n1 = bounds[1];
    float s = 0.f;
    for (int n = n0; n < n1; ++n) s += h[(size_t)n * HID + c];
    float divf = fmaxf((float)(n1 - n0), 1.f);
    pooled[c] = s / divf;
    __syncthreads();
    if (c < NCLASSES) {
        float acc = 0.f;
        for (int j = 0; j < HID; ++j) acc += pooled[j] * W[j * NCLASSES + c];
        lg[c] = acc + b[c];
    }
    __syncthreads();
    if (c == 0) {
        float m = fmaxf(lg[0], fmaxf(lg[1], lg[2]));
        float ssum = 0.f;
        for (int cc = 0; cc < NCLASSES; ++cc) ssum += __expf(lg[cc] - m);
        float lse = logf(ssum);
        for (int cc = 0; cc < NCLASSES; ++cc) out[g * NCLASSES + cc] = lg[cc] - m - lse;
    }
}

extern "C" void kernel_launch(void* const* d_in, const int* in_sizes, int n_in,
                              void* d_out, int out_size, void* d_ws, size_t ws_size,
                              hipStream_t stream) {
    float* out = (float*)d_out;

    static const int EXPECT[23] = {2560000, 2048000, 8192, 64, 512, 64, 4096, 64,
                                   49152, 768, 49152, 768, 49152, 768, 49152,
                                   12288, 192, 192, 192, 192, 3, 512000, 20000};
    int bad = -1;
    if (n_in != 23) bad = 99;
    else {
        for (int i = 0; i < 23; ++i) {
            if (in_sizes[i] != EXPECT[i]) { bad = i; break; }
        }
    }
    if (bad >= 0) {
        float val = (bad == 99) ? 4000.f : (5000.f + 10.f * bad);
        gt_write_const<<<1, 256, 0, stream>>>(out, out_size, val);
        return;
    }

    const float* x        = (const float*)d_in[0];
    const float* edge_attr= (const float*)d_in[1];
    const float* node_W   = (const float*)d_in[2];
    const float* node_b   = (const float*)d_in[3];
    const float* e1_W     = (const float*)d_in[4];
    const float* e1_b     = (const float*)d_in[5];
    const float* e2_W     = (const float*)d_in[6];
    const float* e2_b     = (const float*)d_in[7];
    const float* Wq       = (const float*)d_in[8];
    const float* bq       = (const float*)d_in[9];
    const float* Wk       = (const float*)d_in[10];
    const float* bk       = (const float*)d_in[11];
    const float* Wv       = (const float*)d_in[12];
    const float* bv       = (const float*)d_in[13];
    const float* We       = (const float*)d_in[14];
    const float* Wskip    = (const float*)d_in[15];
    const float* bskip    = (const float*)d_in[16];
    const float* lng      = (const float*)d_in[17];
    const float* lnb      = (const float*)d_in[18];
    const float* cls_W    = (const float*)d_in[19];
    const float* cls_b    = (const float*)d_in[20];
    const int*   ei       = (const int*)d_in[21];
    const int*   batch    = (const int*)d_in[22];

    char* w = (char*)d_ws;
    auto alloc = [&](size_t bytes) -> char* {
        char* p = w;
        w += (bytes + 255) & ~(size_t)255;
        return p;
    };
    float* h     = (float*)alloc((size_t)NN * HID * 4);
    bf16*  ef    = (bf16*)alloc((size_t)NE * HID * 2);
    float* q     = (float*)alloc((size_t)NN * HC * 4);
    bf16*  k     = (bf16*)alloc((size_t)NN * HC * 2);
    bf16*  v     = (bf16*)alloc((size_t)NN * HC * 2);
    float* qe    = (float*)alloc((size_t)NN * HC * 4);
    float* WeT   = (float*)alloc((size_t)NLAYERS * HID * HC * 4);
    int*   cnt   = (int*)alloc((size_t)NN * 4);
    int*   rp    = (int*)alloc((size_t)(NN + 1) * 4);
    int*   cur   = (int*)alloc((size_t)NN * 4);
    int*   csr   = (int*)alloc((size_t)NE * 4);

    gt_node_proj<<<(NN + 3) / 4, 256, 0, stream>>>(x, node_W, node_b, h);
    gt_edge_mlp<<<NE / EB, 256, 0, stream>>>(edge_attr, e1_W, e1_b, e2_W, e2_b, ef);
    gt_transpose_we<<<(NLAYERS * HID * HC + 255) / 256, 256, 0, stream>>>(We, WeT);
    gt_zero_i32<<<(NN + 255) / 256, 256, 0, stream>>>(cnt, NN);
    gt_count_dst<<<(NE + 255) / 256, 256, 0, stream>>>(ei, cnt);
    gt_scan_csr<<<1, 256, 0, stream>>>(cnt, rp, cur);
    gt_fill_csr<<<(NE + 255) / 256, 256, 0, stream>>>(ei, cur, csr);

    for (int l = 0; l < NLAYERS; ++l) {
        const float* Wq_l = Wq + (size_t)l * HID * HC;
        const float* bq_l = bq + (size_t)l * HC;
        const float* Wk_l = Wk + (size_t)l * HID * HC;
        const float* bk_l = bk + (size_t)l * HC;
        const float* Wv_l = Wv + (size_t)l * HID * HC;
        const float* bv_l = bv + (size_t)l * HC;
        const float* We_l = We + (size_t)l * HID * HC;
        const float* WeT_l= WeT + (size_t)l * HID * HC;
        const float* Ws_l = Wskip + (size_t)l * HID * HID;
        const float* bs_l = bskip + (size_t)l * HID;
        const float* lg_l = lng + (size_t)l * HID;
        const float* lb_l = lnb + (size_t)l * HID;

        gt_qkv_qe<<<(NN + NPB - 1) / NPB, 256, 0, stream>>>(h, Wq_l, bq_l, Wk_l, bk_l, Wv_l, bv_l,
                                                            WeT_l, q, k, v, qe);
        gt_attn_fused<<<NN, 256, 0, stream>>>(q, qe, k, v, ef, We_l, rp, csr, ei, Ws_l, bs_l,
                                              lg_l, lb_l, h);
    }

    gt_pool_classify<<<NGRAPHS, HID, 0, stream>>>(h, batch, cls_W, cls_b, out);
}

// Round 18
// 876.400 us; speedup vs baseline: 1.1597x; 1.1597x over previous
//
#include <hip/hip_runtime.h>
#include <hip/hip_bf16.h>
#include <math.h>

#define NN 20000
#define NE 256000
#define NODE_DIM_ 128
#define EDGE_DIM_ 8
#define HID 64
#define HEADS 4
#define NLAYERS 3
#define NCLASSES 3
#define NGRAPHS 64
#define HC 256  // HEADS*HID
#define NPB 8   // nodes per block in qkv
#define ECHUNK 256
#define EB 64   // edges per block in edge_mlp

typedef __hip_bfloat16 bf16;

__device__ __forceinline__ float B2F(bf16 x) { return __bfloat162float(x); }
__device__ __forceinline__ bf16 F2B(float x) { return __float2bfloat16(x); }
__device__ __forceinline__ int clampi(int x, int lo, int hi) { return min(max(x, lo), hi); }

// ---------------- diagnostics ----------------
__global__ void gt_write_const(float* out, int n, float val) {
    int i = blockIdx.x * blockDim.x + threadIdx.x;
    if (i < n) out[i] = val;
}

// ---------------- utility ----------------
__global__ void gt_zero_i32(int* p, int n) {
    int i = blockIdx.x * blockDim.x + threadIdx.x;
    if (i < n) p[i] = 0;
}

// WeT[l][c*HC + h*64 + j] = We[l][j*HC + h*64 + c]  (fp32)
__global__ void gt_transpose_we(const float* __restrict__ We, float* __restrict__ WeT) {
    int idx = blockIdx.x * blockDim.x + threadIdx.x;
    if (idx >= NLAYERS * HID * HC) return;
    int l = idx / (HID * HC);
    int r = idx % (HID * HC);
    int c = r / HC;
    int u = r % HC;
    int hh = u >> 6, j = u & 63;
    WeT[idx] = We[(size_t)l * HID * HC + (size_t)j * HC + hh * 64 + c];
}

// ---------------- h = x @ node_W + node_b  (4 nodes/block) ----------------
__global__ void gt_node_proj(const float* __restrict__ x, const float* __restrict__ W,
                             const float* __restrict__ b, float* __restrict__ h) {
    int t = threadIdx.x;
    int n = blockIdx.x * 4 + (t >> 6);
    int c = t & 63;
    __shared__ float xr[4][NODE_DIM_];
    for (int i = t; i < 4 * NODE_DIM_; i += 256) {
        int nn = blockIdx.x * 4 + i / NODE_DIM_;
        xr[i / NODE_DIM_][i % NODE_DIM_] = (nn < NN) ? x[(size_t)nn * NODE_DIM_ + i % NODE_DIM_] : 0.f;
    }
    __syncthreads();
    if (n >= NN) return;
    float acc = 0.f;
#pragma unroll 8
    for (int j = 0; j < NODE_DIM_; ++j) acc += xr[t >> 6][j] * W[j * HID + c];
    h[(size_t)n * HID + c] = acc + b[c];
}

// ---------------- edge MLP: 64-edge GEMM tile per block, bf16 out ----------------
__global__ void gt_edge_mlp(const float* __restrict__ ea, const float* __restrict__ W1,
                            const float* __restrict__ b1, const float* __restrict__ W2,
                            const float* __restrict__ b2, bf16* __restrict__ ef) {
    int t = threadIdx.x;
    int c = t & 63, slot = t >> 6;
    int e0 = blockIdx.x * EB;
    __shared__ float aS[EB][EDGE_DIM_];
    __shared__ float t1s[EB][HID];
    for (int i = t; i < EB * EDGE_DIM_; i += 256) {
        ((float*)aS)[i] = ea[(size_t)e0 * EDGE_DIM_ + i];
    }
    float w1r[EDGE_DIM_];
#pragma unroll
    for (int j = 0; j < EDGE_DIM_; ++j) w1r[j] = W1[j * HID + c];
    float b1c = b1[c], b2c = b2[c];
    __syncthreads();
#pragma unroll
    for (int es16 = 0; es16 < 16; ++es16) {
        int es = slot * 16 + es16;
        float acc = b1c;
#pragma unroll
        for (int j = 0; j < EDGE_DIM_; ++j) acc += aS[es][j] * w1r[j];
        t1s[es][c] = fmaxf(acc, 0.f);
    }
    __syncthreads();
    float acc2[16];
#pragma unroll
    for (int i = 0; i < 16; ++i) acc2[i] = b2c;
    for (int j = 0; j < HID; ++j) {
        float w = W2[j * HID + c];
#pragma unroll
        for (int es16 = 0; es16 < 16; ++es16) acc2[es16] += t1s[slot * 16 + es16][j] * w;
    }
#pragma unroll
    for (int es16 = 0; es16 < 16; ++es16) {
        int es = slot * 16 + es16;
        ef[(size_t)(e0 + es) * HID + c] = F2B(acc2[es16]);
    }
}

// ---------------- CSR build over dst ----------------
__global__ void gt_count_dst(const int* __restrict__ ei, int* cnt) {
    int e = blockIdx.x * blockDim.x + threadIdx.x;
    if (e < NE) {
        int d = clampi(ei[NE + e], 0, NN - 1);
        atomicAdd(&cnt[d], 1);
    }
}

__global__ void gt_scan_csr(const int* __restrict__ cnt, int* __restrict__ rp, int* __restrict__ cur) {
    __shared__ int part[256];
    int tid = threadIdx.x;
    const int CH = (NN + 255) / 256;
    int s0 = tid * CH, s1 = min(s0 + CH, NN);
    int s = 0;
    for (int i = s0; i < s1; ++i) s += cnt[i];
    part[tid] = s;
    __syncthreads();
    for (int off = 1; off < 256; off <<= 1) {
        int vv = (tid >= off) ? part[tid - off] : 0;
        __syncthreads();
        if (tid >= off) part[tid] += vv;
        __syncthreads();
    }
    int base = (tid == 0) ? 0 : part[tid - 1];
    for (int i = s0; i < s1; ++i) {
        rp[i] = base;
        cur[i] = base;
        base += cnt[i];
    }
    if (tid == 255) rp[NN] = part[255];
}

__global__ void gt_fill_csr(const int* __restrict__ ei, int* cur, int* csr) {
    int e = blockIdx.x * blockDim.x + threadIdx.x;
    if (e < NE) {
        int d = clampi(ei[NE + e], 0, NN - 1);
        int pos = atomicAdd(&cur[d], 1);
        if (pos >= 0 && pos < NE) csr[pos] = e;
    }
}

// ---------------- q,k,v,qe projections (8 nodes/block); fp32 weights, bf16 k/v out ----------------
__global__ void gt_qkv_qe(const float* __restrict__ h, const float* __restrict__ Wq,
                          const float* __restrict__ bq, const float* __restrict__ Wk,
                          const float* __restrict__ bk, const float* __restrict__ Wv,
                          const float* __restrict__ bv, const float* __restrict__ WeT,
                          float* __restrict__ q, bf16* __restrict__ k, bf16* __restrict__ v,
                          float* __restrict__ qe) {
    int t = threadIdx.x;
    int n0 = blockIdx.x * NPB;
    __shared__ float hs[NPB][HID];
    __shared__ float qs[NPB][HC];
    for (int i = t; i < NPB * HID; i += 256) {
        int nn = n0 + i / HID;
        hs[i / HID][i % HID] = (nn < NN) ? h[(size_t)nn * HID + i % HID] : 0.f;
    }
    __syncthreads();
    float aq[NPB], ak[NPB], av[NPB];
#pragma unroll
    for (int i = 0; i < NPB; ++i) { aq[i] = 0.f; ak[i] = 0.f; av[i] = 0.f; }
    for (int j = 0; j < HID; ++j) {
        float wq = Wq[j * HC + t];
        float wk = Wk[j * HC + t];
        float wv = Wv[j * HC + t];
#pragma unroll
        for (int i = 0; i < NPB; ++i) {
            aq[i] += hs[i][j] * wq;
            ak[i] += hs[i][j] * wk;
            av[i] += hs[i][j] * wv;
        }
    }
    float bqv = bq[t], bkv = bk[t], bvv = bv[t];
    for (int i = 0; i < NPB; ++i) {
        int nn = n0 + i;
        float qr = aq[i] + bqv;
        qs[i][t] = qr;
        if (nn < NN) {
            q[(size_t)nn * HC + t] = qr;
            k[(size_t)nn * HC + t] = F2B(ak[i] + bkv);
            v[(size_t)nn * HC + t] = F2B(av[i] + bvv);
        }
    }
    __syncthreads();
    int h2 = t >> 6;
    float accq[NPB];
#pragma unroll
    for (int i = 0; i < NPB; ++i) accq[i] = 0.f;
    for (int c = 0; c < HID; ++c) {
        float wt = WeT[(size_t)c * HC + t];
#pragma unroll
        for (int i = 0; i < NPB; ++i) accq[i] += qs[i][h2 * 64 + c] * wt;
    }
    for (int i = 0; i < NPB; ++i) {
        int nn = n0 + i;
        if (nn < NN) qe[(size_t)nn * HC + t] = accq[i];
    }
}

// ---------------- FUSED attn (R15 structure) + in-place exp precompute ----------------
__global__ void gt_attn_fused(const float* __restrict__ q, const float* __restrict__ qe,
                              const bf16* __restrict__ k, const bf16* __restrict__ v,
                              const bf16* __restrict__ ef, const float* __restrict__ We,
                              const int* __restrict__ rp, const int* __restrict__ csr,
                              const int* __restrict__ ei, const float* __restrict__ Wskip,
                              const float* __restrict__ bskip, const float* __restrict__ lng,
                              const float* __restrict__ lnb, float* __restrict__ h) {
    int n = blockIdx.x;
    int t = threadIdx.x;   // 256 = 4 waves; wave == head
    int lane = t & 63, wave = t >> 6;
    __shared__ float sQ[HC];
    __shared__ float sQe[HC];
    __shared__ int sE[ECHUNK];
    __shared__ int sSrc[ECHUNK];
    __shared__ float4 sAl[ECHUNK];
    __shared__ float sS[HC];
    __shared__ float sC[HC];
    __shared__ float res[HID];
    sQ[t] = q[(size_t)n * HC + t];
    sQe[t] = qe[(size_t)n * HC + t];
    if (t < HID) res[t] = h[(size_t)n * HID + t];
    int s0 = clampi(rp[n], 0, NE), s1 = clampi(rp[n + 1], s0, NE);
    float mrun = -1e30f, lrun = 0.f, accv = 0.f, accs = 0.f;
    for (int base = s0; base < s1; base += ECHUNK) {
        int m = min(ECHUNK, s1 - base);
        __syncthreads();
        if (t < m) {
            int e = clampi(csr[base + t], 0, NE - 1);
            sE[t] = e;
            sSrc[t] = clampi(ei[e], 0, NN - 1);
        }
        __syncthreads();
        // raw alpha per edge (one wave per edge, 4 heads at once) — R15 scheme
        for (int i = wave; i < m; i += 4) {
            const bf16* kk = &k[(size_t)sSrc[i] * HC];
            float efc = B2F(ef[(size_t)sE[i] * HID + lane]);
            float p0 = sQ[lane] * B2F(kk[lane]) + sQe[lane] * efc;
            float p1 = sQ[64 + lane] * B2F(kk[64 + lane]) + sQe[64 + lane] * efc;
            float p2 = sQ[128 + lane] * B2F(kk[128 + lane]) + sQe[128 + lane] * efc;
            float p3 = sQ[192 + lane] * B2F(kk[192 + lane]) + sQe[192 + lane] * efc;
#pragma unroll
            for (int s = 32; s > 0; s >>= 1) {
                p0 += __shfl_down(p0, s, 64);
                p1 += __shfl_down(p1, s, 64);
                p2 += __shfl_down(p2, s, 64);
                p3 += __shfl_down(p3, s, 64);
            }
            if (lane == 0) {
                float4 r;
                r.x = p0 * 0.125f; r.y = p1 * 0.125f; r.z = p2 * 0.125f; r.w = p3 * 0.125f;
                sAl[i] = r;
            }
        }
        __syncthreads();
        // chunk max for this wave's head
        float cmax = -1e30f;
        for (int i = lane; i < m; i += 64) cmax = fmaxf(cmax, ((const float*)&sAl[i])[wave]);
#pragma unroll
        for (int s = 32; s > 0; s >>= 1) cmax = fmaxf(cmax, __shfl_xor(cmax, s, 64));
        float newm = fmaxf(mrun, cmax);
        float scale = __expf(mrun - newm);
        accv *= scale; accs *= scale; lrun *= scale;
        mrun = newm;
        // in-place exp: wave w rewrites only component [w] of each sAl[i] —
        // disjoint bytes across waves, wave-coherent reads below, no barrier,
        // no extra LDS, no extra VGPR (vs R17's sW which halved occupancy).
        for (int i = lane; i < m; i += 64) {
            float* p = (float*)&sAl[i];
            p[wave] = __expf(p[wave] - mrun);
        }
#pragma unroll 4
        for (int i = 0; i < m; ++i) {
            float wgt = ((const float*)&sAl[i])[wave];
            lrun += wgt;
            accv += wgt * B2F(v[(size_t)sSrc[i] * HC + t]);
            accs += wgt * B2F(ef[(size_t)sE[i] * HID + lane]);
        }
    }
    float inv = (s1 > s0) ? (1.f / lrun) : 0.f;
    sS[t] = accs * inv;
    float accvn = accv * inv;
    __syncthreads();
    float proj = 0.f;
    const float* srow = &sS[wave * 64];
#pragma unroll 8
    for (int j = 0; j < HID; ++j) proj += srow[j] * We[(size_t)j * HC + t];
    sC[t] = accvn + proj;
    __syncthreads();
    if (t < HID) {
        float conv = 0.25f * (sC[t] + sC[HID + t] + sC[2 * HID + t] + sC[3 * HID + t]);
        float sk = bskip[t];
#pragma unroll 8
        for (int j = 0; j < HID; ++j) sk += res[j] * Wskip[j * HID + t];
        float y = conv + sk + res[t];
        float mm = y;
#pragma unroll
        for (int s = 32; s > 0; s >>= 1) mm += __shfl_xor(mm, s, 64);
        mm *= (1.f / HID);
        float d = y - mm;
        float vv = d * d;
#pragma unroll
        for (int s = 32; s > 0; s >>= 1) vv += __shfl_xor(vv, s, 64);
        vv *= (1.f / HID);
        float o = d * rsqrtf(vv + 1e-5f) * lng[t] + lnb[t];
        h[(size_t)n * HID + t] = fmaxf(o, 0.f);
    }
}

// ---------------- pool (true count) + classifier ----------------
__global__ void gt_pool_classify(const float* __restrict__ h, const int* __restrict__ batch,
                                 const float* __restrict__ W, const float* __restrict__ b,
                                 float* __restrict__ out) {
    int g = blockIdx.x;
    int c = threadIdx.x;
    __shared__ float pooled[HID];
    __shared__ float lg[4];
    __shared__ int bounds[2];
    if (c < 2) {
        int target = g + c;
        int lo = 0, hi = NN;
        while (lo < hi) {
            int mid = (lo + hi) >> 1;
            if (batch[mid] < target) lo = mid + 1; else hi = mid;
        }
        bounds[c] = lo;
    }
    __syncthreads();
    int n0 = bounds[0], n1 = bounds[1];
    float s = 0.f;
    for (int n = n0; n < n1; ++n) s += h[(size_t)n * HID + c];
    float divf = fmaxf((float)(n1 - n0), 1.f);
    pooled[c] = s / divf;
    __syncthreads();
    if (c < NCLASSES) {
        float acc = 0.f;
        for (int j = 0; j < HID; ++j) acc += pooled[j] * W[j * NCLASSES + c];
        lg[c] = acc + b[c];
    }
    __syncthreads();
    if (c == 0) {
        float m = fmaxf(lg[0], fmaxf(lg[1], lg[2]));
        float ssum = 0.f;
        for (int cc = 0; cc < NCLASSES; ++cc) ssum += __expf(lg[cc] - m);
        float lse = logf(ssum);
        for (int cc = 0; cc < NCLASSES; ++cc) out[g * NCLASSES + cc] = lg[cc] - m - lse;
    }
}

extern "C" void kernel_launch(void* const* d_in, const int* in_sizes, int n_in,
                              void* d_out, int out_size, void* d_ws, size_t ws_size,
                              hipStream_t stream) {
    float* out = (float*)d_out;

    static const int EXPECT[23] = {2560000, 2048000, 8192, 64, 512, 64, 4096, 64,
                                   49152, 768, 49152, 768, 49152, 768, 49152,
                                   12288, 192, 192, 192, 192, 3, 512000, 20000};
    int bad = -1;
    if (n_in != 23) bad = 99;
    else {
        for (int i = 0; i < 23; ++i) {
            if (in_sizes[i] != EXPECT[i]) { bad = i; break; }
        }
    }
    if (bad >= 0) {
        float val = (bad == 99) ? 4000.f : (5000.f + 10.f * bad);
        gt_write_const<<<1, 256, 0, stream>>>(out, out_size, val);
        return;
    }

    const float* x        = (const float*)d_in[0];
    const float* edge_attr= (const float*)d_in[1];
    const float* node_W   = (const float*)d_in[2];
    const float* node_b   = (const float*)d_in[3];
    const float* e1_W     = (const float*)d_in[4];
    const float* e1_b     = (const float*)d_in[5];
    const float* e2_W     = (const float*)d_in[6];
    const float* e2_b     = (const float*)d_in[7];
    const float* Wq       = (const float*)d_in[8];
    const float* bq       = (const float*)d_in[9];
    const float* Wk       = (const float*)d_in[10];
    const float* bk       = (const float*)d_in[11];
    const float* Wv       = (const float*)d_in[12];
    const float* bv       = (const float*)d_in[13];
    const float* We       = (const float*)d_in[14];
    const float* Wskip    = (const float*)d_in[15];
    const float* bskip    = (const float*)d_in[16];
    const float* lng      = (const float*)d_in[17];
    const float* lnb      = (const float*)d_in[18];
    const float* cls_W    = (const float*)d_in[19];
    const float* cls_b    = (const float*)d_in[20];
    const int*   ei       = (const int*)d_in[21];
    const int*   batch    = (const int*)d_in[22];

    char* w = (char*)d_ws;
    auto alloc = [&](size_t bytes) -> char* {
        char* p = w;
        w += (bytes + 255) & ~(size_t)255;
        return p;
    };
    float* h     = (float*)alloc((size_t)NN * HID * 4);
    bf16*  ef    = (bf16*)alloc((size_t)NE * HID * 2);
    float* q     = (float*)alloc((size_t)NN * HC * 4);
    bf16*  k     = (bf16*)alloc((size_t)NN * HC * 2);
    bf16*  v     = (bf16*)alloc((size_t)NN * HC * 2);
    float* qe    = (float*)alloc((size_t)NN * HC * 4);
    float* WeT   = (float*)alloc((size_t)NLAYERS * HID * HC * 4);
    int*   cnt   = (int*)alloc((size_t)NN * 4);
    int*   rp    = (int*)alloc((size_t)(NN + 1) * 4);
    int*   cur   = (int*)alloc((size_t)NN * 4);
    int*   csr   = (int*)alloc((size_t)NE * 4);

    gt_node_proj<<<(NN + 3) / 4, 256, 0, stream>>>(x, node_W, node_b, h);
    gt_edge_mlp<<<NE / EB, 256, 0, stream>>>(edge_attr, e1_W, e1_b, e2_W, e2_b, ef);
    gt_transpose_we<<<(NLAYERS * HID * HC + 255) / 256, 256, 0, stream>>>(We, WeT);
    gt_zero_i32<<<(NN + 255) / 256, 256, 0, stream>>>(cnt, NN);
    gt_count_dst<<<(NE + 255) / 256, 256, 0, stream>>>(ei, cnt);
    gt_scan_csr<<<1, 256, 0, stream>>>(cnt, rp, cur);
    gt_fill_csr<<<(NE + 255) / 256, 256, 0, stream>>>(ei, cur, csr);

    for (int l = 0; l < NLAYERS; ++l) {
        const float* Wq_l = Wq + (size_t)l * HID * HC;
        const float* bq_l = bq + (size_t)l * HC;
        const float* Wk_l = Wk + (size_t)l * HID * HC;
        const float* bk_l = bk + (size_t)l * HC;
        const float* Wv_l = Wv + (size_t)l * HID * HC;
        const float* bv_l = bv + (size_t)l * HC;
        const float* We_l = We + (size_t)l * HID * HC;
        const float* WeT_l= WeT + (size_t)l * HID * HC;
        const float* Ws_l = Wskip + (size_t)l * HID * HID;
        const float* bs_l = bskip + (size_t)l * HID;
        const float* lg_l = lng + (size_t)l * HID;
        const float* lb_l = lnb + (size_t)l * HID;

        gt_qkv_qe<<<(NN + NPB - 1) / NPB, 256, 0, stream>>>(h, Wq_l, bq_l, Wk_l, bk_l, Wv_l, bv_l,
                                                            WeT_l, q, k, v, qe);
        gt_attn_fused<<<NN, 256, 0, stream>>>(q, qe, k, v, ef, We_l, rp, csr, ei, Ws_l, bs_l,
                                              lg_l, lb_l, h);
    }

    gt_pool_classify<<<NGRAPHS, HID, 0, stream>>>(h, batch, cls_W, cls_b, out);
}